// Round 1
// baseline (215.171 us; speedup 1.0000x reference)
//
#include <hip/hip_runtime.h>

typedef __attribute__((ext_vector_type(8))) __bf16 bf16x8;
typedef __attribute__((ext_vector_type(4))) float f32x4;
typedef unsigned short u16;

#define MFMA16(a, b, c) __builtin_amdgcn_mfma_f32_16x16x32_bf16(a, b, c, 0, 0, 0)

__device__ __forceinline__ u16 f2bf(float f) {
    unsigned u = __float_as_uint(f);
    unsigned r = ((u >> 16) & 1u) + 0x7fffu;  // RNE
    return (u16)((u + r) >> 16);
}
__device__ __forceinline__ float bf2f(u16 h) {
    return __uint_as_float(((unsigned)h) << 16);
}
// LDS fragment: row = rtile + (lane&15), k = kofs + (lane>>4)*8; row stride 72 u16 (144B)
__device__ __forceinline__ bf16x8 frag(const u16* base, int rtile, int lane, int kofs) {
    return *(const bf16x8*)(base + (rtile + (lane & 15)) * 72 + kofs + (lane >> 4) * 8);
}

// ---------------------------------------------------------------------------
// Fused partial: for k-half ks (blockIdx.y), 64 rows (blockIdx.x):
//   Qp[ks] = x*Wq^T, Kp[ks] = x*Wk^T (fp32 partials)
//   fcp[ks] = x*W1^T (fp32, 3-product bf16 split)
// 512 blocks -> 2 blocks/CU, 8 waves/CU.
// ---------------------------------------------------------------------------
__global__ __launch_bounds__(256) void qkf_kernel(
    const float* __restrict__ x, const float* __restrict__ Wq,
    const float* __restrict__ Wk, const float* __restrict__ W1,
    float* __restrict__ Qp, float* __restrict__ Kp, float* __restrict__ fcp)
{
    __shared__ __align__(16) u16 SM[6 * 4608];
    u16* Xh  = SM;
    u16* Xl  = SM + 4608;
    u16* Wqh = SM + 2 * 4608;
    u16* Wkh = SM + 3 * 4608;
    u16* W1h = SM + 4 * 4608;
    u16* W1l = SM + 5 * 4608;

    const int tid  = threadIdx.x;
    const int lane = tid & 63;
    const int wv   = tid >> 6;
    const int r0   = wv * 16;
    const long row0 = (long)blockIdx.x * 64;
    const int kb   = blockIdx.y * 512;          // k-half base
    const long sOf = (long)blockIdx.y * 1048576; // output slab offset

    const f32x4 zero = {0.f, 0.f, 0.f, 0.f};
    f32x4 qa[4], ka[4], fa[4];
#pragma unroll
    for (int i = 0; i < 4; ++i) { qa[i] = zero; ka[i] = zero; fa[i] = zero; }

    const int sr = tid >> 4;         // staging row 0..15
    const int sk = (tid & 15) * 4;   // staging k   0..60

    float4 xv[4], qv[4], kv[4], w1v[4];
#define QKF_LOAD(K0)                                                          \
    {                                                                         \
        _Pragma("unroll")                                                     \
        for (int i = 0; i < 4; ++i) {                                         \
            int r = sr + i * 16;                                              \
            xv[i]  = *(const float4*)(x  + (row0 + r) * 1024 + (K0) + sk);    \
            qv[i]  = *(const float4*)(Wq + (long)r * 1024 + (K0) + sk);       \
            kv[i]  = *(const float4*)(Wk + (long)r * 1024 + (K0) + sk);       \
            w1v[i] = *(const float4*)(W1 + (long)r * 1024 + (K0) + sk);       \
        }                                                                     \
    }

    QKF_LOAD(kb)
    for (int ch = 0; ch < 8; ++ch) {
        if (ch) __syncthreads();
#pragma unroll
        for (int i = 0; i < 4; ++i) {
            int r = sr + i * 16;
            ushort4 h, l;
            h.x = f2bf(xv[i].x); l.x = f2bf(xv[i].x - bf2f(h.x));
            h.y = f2bf(xv[i].y); l.y = f2bf(xv[i].y - bf2f(h.y));
            h.z = f2bf(xv[i].z); l.z = f2bf(xv[i].z - bf2f(h.z));
            h.w = f2bf(xv[i].w); l.w = f2bf(xv[i].w - bf2f(h.w));
            *(ushort4*)&Xh[r * 72 + sk] = h;
            *(ushort4*)&Xl[r * 72 + sk] = l;
            ushort4 hq;
            hq.x = f2bf(qv[i].x); hq.y = f2bf(qv[i].y);
            hq.z = f2bf(qv[i].z); hq.w = f2bf(qv[i].w);
            *(ushort4*)&Wqh[r * 72 + sk] = hq;
            ushort4 hk;
            hk.x = f2bf(kv[i].x); hk.y = f2bf(kv[i].y);
            hk.z = f2bf(kv[i].z); hk.w = f2bf(kv[i].w);
            *(ushort4*)&Wkh[r * 72 + sk] = hk;
            ushort4 hw, lw;
            hw.x = f2bf(w1v[i].x); lw.x = f2bf(w1v[i].x - bf2f(hw.x));
            hw.y = f2bf(w1v[i].y); lw.y = f2bf(w1v[i].y - bf2f(hw.y));
            hw.z = f2bf(w1v[i].z); lw.z = f2bf(w1v[i].z - bf2f(hw.z));
            hw.w = f2bf(w1v[i].w); lw.w = f2bf(w1v[i].w - bf2f(hw.w));
            *(ushort4*)&W1h[r * 72 + sk] = hw;
            *(ushort4*)&W1l[r * 72 + sk] = lw;
        }
        __syncthreads();
        if (ch < 7) QKF_LOAD(kb + (ch + 1) * 64)
#pragma unroll
        for (int kk = 0; kk < 64; kk += 32) {
            bf16x8 ah = frag(Xh, r0, lane, kk);
            bf16x8 al = frag(Xl, r0, lane, kk);
#pragma unroll
            for (int ct = 0; ct < 4; ++ct) {
                qa[ct] = MFMA16(ah, frag(Wqh, ct * 16, lane, kk), qa[ct]);
                ka[ct] = MFMA16(ah, frag(Wkh, ct * 16, lane, kk), ka[ct]);
                bf16x8 bh = frag(W1h, ct * 16, lane, kk);
                fa[ct] = MFMA16(ah, bh, fa[ct]);
                fa[ct] = MFMA16(al, bh, fa[ct]);
                fa[ct] = MFMA16(ah, frag(W1l, ct * 16, lane, kk), fa[ct]);
            }
        }
    }
#undef QKF_LOAD

    // fp32 partial stores (C layout: col=lane&15, row=quad*4+g)
    const int rr = r0 + (lane >> 4) * 4;
    const int cc = lane & 15;
#pragma unroll
    for (int ct = 0; ct < 4; ++ct)
#pragma unroll
        for (int g = 0; g < 4; ++g) {
            long o = sOf + (row0 + rr + g) * 64 + ct * 16 + cc;
            Qp[o]  = qa[ct][g];
            Kp[o]  = ka[ct][g];
            fcp[o] = fa[ct][g];
        }
}

// ---------------------------------------------------------------------------
// Sp[ks][b][j][d] = sum_{n in ks-slice} K[b,n,j] * x[b,n,d]
// K comes as 2 fp32 slabs (summed at staging). grid (16,8,8) = 1024 blocks.
// ---------------------------------------------------------------------------
__global__ __launch_bounds__(256) void s_kernel(
    const float* __restrict__ Kp, const float* __restrict__ x,
    float* __restrict__ Sp)
{
    __shared__ __align__(16) u16 Kt[64 * 72];
    __shared__ __align__(16) u16 Xt[64 * 72];

    const int tid = threadIdx.x, lane = tid & 63, wv = tid >> 6;
    const int dt = blockIdx.x, ks = blockIdx.y, b = blockIdx.z;
    const int n0 = ks * 256, d0 = dt * 64;

    const float* Kq = Kp + ((long)b * 2048 + n0) * 64;
    const float* xp = x  + ((long)b * 2048 + n0) * 1024 + d0;

    const f32x4 zero = {0.f, 0.f, 0.f, 0.f};
    f32x4 acc[4];
#pragma unroll
    for (int i = 0; i < 4; ++i) acc[i] = zero;

    float4 kf[4], xv[4];
#define SK_LOAD(NB)                                                           \
    {                                                                         \
        _Pragma("unroll")                                                     \
        for (int i = 0; i < 4; ++i) {                                         \
            float4 a = *(const float4*)(Kq + (long)((NB) + lane) * 64 + wv * 16 + i * 4); \
            float4 c = *(const float4*)(Kq + 1048576 + (long)((NB) + lane) * 64 + wv * 16 + i * 4); \
            kf[i].x = a.x + c.x; kf[i].y = a.y + c.y;                         \
            kf[i].z = a.z + c.z; kf[i].w = a.w + c.w;                         \
            xv[i] = *(const float4*)(xp + (long)((NB) + lane) * 1024 + wv * 16 + i * 4); \
        }                                                                     \
    }

    SK_LOAD(0)
    for (int ch = 0; ch < 4; ++ch) {
        if (ch) __syncthreads();
#pragma unroll
        for (int i = 0; i < 4; ++i) {
            Kt[(wv * 16 + i * 4 + 0) * 72 + lane] = f2bf(kf[i].x);
            Kt[(wv * 16 + i * 4 + 1) * 72 + lane] = f2bf(kf[i].y);
            Kt[(wv * 16 + i * 4 + 2) * 72 + lane] = f2bf(kf[i].z);
            Kt[(wv * 16 + i * 4 + 3) * 72 + lane] = f2bf(kf[i].w);
            Xt[(wv * 16 + i * 4 + 0) * 72 + lane] = f2bf(xv[i].x);
            Xt[(wv * 16 + i * 4 + 1) * 72 + lane] = f2bf(xv[i].y);
            Xt[(wv * 16 + i * 4 + 2) * 72 + lane] = f2bf(xv[i].z);
            Xt[(wv * 16 + i * 4 + 3) * 72 + lane] = f2bf(xv[i].w);
        }
        __syncthreads();
        if (ch < 3) SK_LOAD((ch + 1) * 64)
#pragma unroll
        for (int kk = 0; kk < 64; kk += 32) {
            bf16x8 a = frag(Kt, wv * 16, lane, kk);
#pragma unroll
            for (int ct = 0; ct < 4; ++ct)
                acc[ct] = MFMA16(a, frag(Xt, ct * 16, lane, kk), acc[ct]);
        }
    }
#undef SK_LOAD

    float* C = Sp + ((long)ks * 8 + b) * 65536 + d0;
    const int rr = wv * 16 + (lane >> 4) * 4;
    const int cc = lane & 15;
#pragma unroll
    for (int ct = 0; ct < 4; ++ct)
#pragma unroll
        for (int g = 0; g < 4; ++g)
            C[(long)(rr + g) * 1024 + ct * 16 + cc] = acc[ct][g];
}

// ---------------------------------------------------------------------------
// 64x64 MFMA NT-GEMM: C[m,n] = sum_s Cin_s[m,n] + sum_k (sum A_s)*(sum B_s)
// AMODE: 0 fp32 row-major, 1 bf16 row-major.
// BMODE: 0 fp32 row-major, 1 bf16 row-major, 2 fp32 transposed [k][n].
// SPLIT: hi/lo 3-product accuracy. CSLAB: #fp32 C-init slabs (0 = none).
// ---------------------------------------------------------------------------
template <int AMODE, int BMODE, bool SPLIT, int ASLAB, int BSLAB, int CSLAB>
__global__ __launch_bounds__(256) void mm_nt(
    const void* __restrict__ Ap, int lda, long bsA, long slabA,
    const void* __restrict__ Bp, int ldb, long bsB, long slabB,
    float* __restrict__ Cp, int ldc, long bsC, long splitC,
    const float* __restrict__ Cin, long slabCin,
    int Kred, int nksplit)
{
    __shared__ __align__(16) u16 SMEM[(SPLIT ? 4 : 2) * 4608];
    u16* Ah = SMEM;
    u16* Bh = SMEM + 4608;
    u16* Al = SPLIT ? SMEM + 2 * 4608 : nullptr;
    u16* Bl = SPLIT ? SMEM + 3 * 4608 : nullptr;

    const int tid = threadIdx.x, lane = tid & 63, wv = tid >> 6;
    const int bm = blockIdx.x, bn = blockIdx.y;
    const int batch = blockIdx.z / nksplit;
    const int ks = blockIdx.z % nksplit;
    const int Kper = Kred / nksplit;
    const long kOff = (long)ks * Kper;

    const int r4 = tid >> 4, k4 = (tid & 15) * 4;   // mode-0 staging coords
    const int r8 = tid >> 3, k8 = (tid & 7) * 8;    // mode-1 staging coords

    const f32x4 zero = {0.f, 0.f, 0.f, 0.f};
    f32x4 acc[4];
#pragma unroll
    for (int i = 0; i < 4; ++i) acc[i] = zero;

    float4 fva[4], fvb[4];
    uint4  uva[2], uvb[2];
    float  tvb[16];

#define MM_LOADA(K0)                                                          \
    if constexpr (AMODE == 0) {                                               \
        const float* A = (const float*)Ap + (long)batch * bsA                 \
                       + (long)bm * 64 * lda + (K0);                          \
        _Pragma("unroll")                                                     \
        for (int i = 0; i < 4; ++i) {                                         \
            const float* p = A + (long)(r4 + i * 16) * lda + k4;              \
            float4 v = *(const float4*)p;                                     \
            _Pragma("unroll")                                                 \
            for (int s = 1; s < ASLAB; ++s) {                                 \
                float4 w = *(const float4*)(p + (long)s * slabA);             \
                v.x += w.x; v.y += w.y; v.z += w.z; v.w += w.w;               \
            }                                                                 \
            fva[i] = v;                                                       \
        }                                                                     \
    } else {                                                                  \
        const u16* A = (const u16*)Ap + (long)batch * bsA                     \
                     + (long)bm * 64 * lda + (K0);                            \
        _Pragma("unroll")                                                     \
        for (int i = 0; i < 2; ++i)                                           \
            uva[i] = *(const uint4*)(A + (long)(r8 + i * 32) * lda + k8);     \
    }
#define MM_LOADB(K0)                                                          \
    if constexpr (BMODE == 0) {                                               \
        const float* Bq = (const float*)Bp + (long)batch * bsB                \
                        + (long)bn * 64 * ldb + (K0);                         \
        _Pragma("unroll")                                                     \
        for (int i = 0; i < 4; ++i) {                                         \
            const float* p = Bq + (long)(r4 + i * 16) * ldb + k4;             \
            float4 v = *(const float4*)p;                                     \
            _Pragma("unroll")                                                 \
            for (int s = 1; s < BSLAB; ++s) {                                 \
                float4 w = *(const float4*)(p + (long)s * slabB);             \
                v.x += w.x; v.y += w.y; v.z += w.z; v.w += w.w;               \
            }                                                                 \
            fvb[i] = v;                                                       \
        }                                                                     \
    } else if constexpr (BMODE == 1) {                                        \
        const u16* Bq = (const u16*)Bp + (long)batch * bsB                    \
                      + (long)bn * 64 * ldb + (K0);                           \
        _Pragma("unroll")                                                     \
        for (int i = 0; i < 2; ++i)                                           \
            uvb[i] = *(const uint4*)(Bq + (long)(r8 + i * 32) * ldb + k8);    \
    } else {                                                                  \
        const float* Bq = (const float*)Bp + (long)batch * bsB                \
                        + (long)(K0) * ldb + (long)bn * 64;                   \
        _Pragma("unroll")                                                     \
        for (int i = 0; i < 16; ++i)                                          \
            tvb[i] = Bq[(long)((tid >> 6) + i * 4) * ldb + (tid & 63)];       \
    }

    MM_LOADA(kOff) MM_LOADB(kOff)
    for (int k0 = 0; k0 < Kper; k0 += 64) {
        if (k0) __syncthreads();
        // ---- store phase A ----
        if constexpr (AMODE == 0) {
#pragma unroll
            for (int i = 0; i < 4; ++i) {
                int r = r4 + i * 16;
                ushort4 h;
                h.x = f2bf(fva[i].x); h.y = f2bf(fva[i].y);
                h.z = f2bf(fva[i].z); h.w = f2bf(fva[i].w);
                *(ushort4*)&Ah[r * 72 + k4] = h;
                if constexpr (SPLIT) {
                    ushort4 l;
                    l.x = f2bf(fva[i].x - bf2f(h.x)); l.y = f2bf(fva[i].y - bf2f(h.y));
                    l.z = f2bf(fva[i].z - bf2f(h.z)); l.w = f2bf(fva[i].w - bf2f(h.w));
                    *(ushort4*)&Al[r * 72 + k4] = l;
                }
            }
        } else {
#pragma unroll
            for (int i = 0; i < 2; ++i)
                *(uint4*)&Ah[(r8 + i * 32) * 72 + k8] = uva[i];
        }
        // ---- store phase B ----
        if constexpr (BMODE == 0) {
#pragma unroll
            for (int i = 0; i < 4; ++i) {
                int r = r4 + i * 16;
                ushort4 h;
                h.x = f2bf(fvb[i].x); h.y = f2bf(fvb[i].y);
                h.z = f2bf(fvb[i].z); h.w = f2bf(fvb[i].w);
                *(ushort4*)&Bh[r * 72 + k4] = h;
                if constexpr (SPLIT) {
                    ushort4 l;
                    l.x = f2bf(fvb[i].x - bf2f(h.x)); l.y = f2bf(fvb[i].y - bf2f(h.y));
                    l.z = f2bf(fvb[i].z - bf2f(h.z)); l.w = f2bf(fvb[i].w - bf2f(h.w));
                    *(ushort4*)&Bl[r * 72 + k4] = l;
                }
            }
        } else if constexpr (BMODE == 1) {
#pragma unroll
            for (int i = 0; i < 2; ++i)
                *(uint4*)&Bh[(r8 + i * 32) * 72 + k8] = uvb[i];
        } else {
#pragma unroll
            for (int i = 0; i < 16; ++i)
                Bh[(tid & 63) * 72 + (tid >> 6) + i * 4] = f2bf(tvb[i]);
        }
        __syncthreads();
        if (k0 + 64 < Kper) { MM_LOADA(kOff + k0 + 64) MM_LOADB(kOff + k0 + 64) }
#pragma unroll
        for (int kk = 0; kk < 64; kk += 32) {
            bf16x8 ah = frag(Ah, wv * 16, lane, kk);
            bf16x8 al;
            if constexpr (SPLIT) al = frag(Al, wv * 16, lane, kk);
#pragma unroll
            for (int ct = 0; ct < 4; ++ct) {
                bf16x8 bh = frag(Bh, ct * 16, lane, kk);
                acc[ct] = MFMA16(ah, bh, acc[ct]);
                if constexpr (SPLIT) {
                    acc[ct] = MFMA16(al, bh, acc[ct]);
                    acc[ct] = MFMA16(ah, frag(Bl, ct * 16, lane, kk), acc[ct]);
                }
            }
        }
    }
#undef MM_LOADA
#undef MM_LOADB

    const long coff = (long)batch * bsC + (long)bm * 64 * ldc + (long)bn * 64;
    float* C = Cp + coff + (long)ks * splitC;
    const int rr = wv * 16 + (lane >> 4) * 4;
    const int cc = lane & 15;
#pragma unroll
    for (int ct = 0; ct < 4; ++ct)
#pragma unroll
        for (int g = 0; g < 4; ++g) {
            long idx = (long)(rr + g) * ldc + ct * 16 + cc;
            float v = acc[ct][g];
            if constexpr (CSLAB > 0) {
                const float* Ci = Cin + coff + idx;
#pragma unroll
                for (int s = 0; s < CSLAB; ++s) v += Ci[(long)s * slabCin];
            }
            C[idx] = v;
        }
}

// ---------------------------------------------------------------------------
extern "C" void kernel_launch(void* const* d_in, const int* in_sizes, int n_in,
                              void* d_out, int out_size, void* d_ws, size_t ws_size,
                              hipStream_t stream)
{
    const float* x  = (const float*)d_in[0];
    const float* Wq = (const float*)d_in[1];
    const float* Wk = (const float*)d_in[2];
    const float* Wv = (const float*)d_in[3];
    const float* W1 = (const float*)d_in[4];
    const float* W2 = (const float*)d_in[5];
    float* out = (float*)d_out;

    // Scratch (bytes): Qp 8M (2 slabs), Kp 8M, fcp 8M, Sp 16M, Gp 2M, PBp 2M, fcb 4M
    const size_t QPB = 8388608, KPB = 8388608, FCPB = 8388608,
                 SPB = 16777216, GPB = 2097152, PBB = 2097152, FCB = 4194304;
    const size_t need = QPB + KPB + FCPB + SPB + GPB + PBB + FCB;  // 50 MB

    float *Qp, *Kp, *fcp, *Sp, *Gp, *PBp, *fcb;
    if (ws_size >= need) {
        char* w = (char*)d_ws;
        Qp  = (float*)w;  w += QPB;
        Kp  = (float*)w;  w += KPB;
        fcp = (float*)w;  w += FCPB;
        Sp  = (float*)w;  w += SPB;
        Gp  = (float*)w;  w += GPB;
        PBp = (float*)w;  w += PBB;
        fcb = (float*)w;
    } else {
        // Scratch in d_out (all dead before the final GEMM overwrites it);
        // fcb (read concurrently with out writes) in ws.
        char* o = (char*)d_out;
        Qp  = (float*)o;  o += QPB;
        Kp  = (float*)o;  o += KPB;
        fcp = (float*)o;  o += FCPB;
        Sp  = (float*)o;  o += SPB;
        Gp  = (float*)o;  o += GPB;
        PBp = (float*)o;
        fcb = (float*)d_ws;
    }

    // 1) Qp/Kp/fcp partials over k-halves (512 blocks, 2/CU)
    qkf_kernel<<<dim3(256, 2), 256, 0, stream>>>(x, Wq, Wk, W1, Qp, Kp, fcp);

    // 2) Sp[ks8][b][j][d] = (Kp0+Kp1)_slice^T * x_slice  (1024 blocks)
    s_kernel<<<dim3(16, 8, 8), 256, 0, stream>>>(Kp, x, Sp);

    // 3) Gpart[ks8][k][d] = W1[k,:] * Wv[:,d]  (batch-independent, 128 blocks)
    mm_nt<0, 2, false, 1, 1, 0><<<dim3(1, 16, 8), 256, 0, stream>>>(
        W1, 1024, 0, 0,   Wv, 1024, 0, 0,
        Gp, 1024, 0, 65536L, nullptr, 0, 1024, 8);

    // 4) PBTpart[ks16][b][k][j] = (sum_8 Gpart)[k,:] * (sum_8 Sp)[b][j,:]^T  (128 blocks)
    mm_nt<0, 0, false, 8, 8, 0><<<dim3(1, 1, 128), 256, 0, stream>>>(
        Gp, 1024, 0, 65536L,   Sp, 1024, 65536L, 524288L,
        PBp, 64, 4096L, 32768L, nullptr, 0, 1024, 16);

    // 5) fcb = fcp0 + fcp1 + (Qp0+Qp1) * (sum_16 PBTpart)^T  (256 blocks)
    mm_nt<0, 0, false, 2, 16, 2><<<dim3(32, 1, 8), 256, 0, stream>>>(
        Qp, 64, 131072L, 1048576L,   PBp, 64, 4096L, 32768L,
        fcb, 64, 131072L, 0, fcp, 1048576L, 64, 1);

    // 6) out = fcb * W2^T (split-accurate both operands, 4096 blocks)
    mm_nt<0, 0, true, 1, 1, 0><<<dim3(256, 16, 1), 256, 0, stream>>>(
        fcb, 64, 0, 0,   W2, 64, 0, 0,
        out, 1024, 0, 0, nullptr, 0, 64, 1);
}

// Round 2
// 213.084 us; speedup vs baseline: 1.0098x; 1.0098x over previous
//
#include <hip/hip_runtime.h>

typedef __attribute__((ext_vector_type(8))) __bf16 bf16x8;
typedef __attribute__((ext_vector_type(4))) float f32x4;
typedef unsigned short u16;

#define MFMA16(a, b, c) __builtin_amdgcn_mfma_f32_16x16x32_bf16(a, b, c, 0, 0, 0)

__device__ __forceinline__ u16 f2bf(float f) {
    unsigned u = __float_as_uint(f);
    unsigned r = ((u >> 16) & 1u) + 0x7fffu;  // RNE
    return (u16)((u + r) >> 16);
}
__device__ __forceinline__ float bf2f(u16 h) {
    return __uint_as_float(((unsigned)h) << 16);
}
// LDS fragment: row = rtile + (lane&15), k = kofs + (lane>>4)*8; row stride 72 u16 (144B)
__device__ __forceinline__ bf16x8 frag(const u16* base, int rtile, int lane, int kofs) {
    return *(const bf16x8*)(base + (rtile + (lane & 15)) * 72 + kofs + (lane >> 4) * 8);
}

// ---------------------------------------------------------------------------
// Fused partial: for k-half ks (blockIdx.y), 64 rows (blockIdx.x):
//   Qp[ks] = x*Wq^T, Kp[ks] = x*Wk^T (fp32 partials)
//   fcp[ks] = x*W1^T (fp32, 3-product bf16 split)
// 512 threads / 8 waves per block; wave = (rtile 0..3) x (ct-half 0..1).
// LDS 55KB -> 2 blocks/CU -> 16 waves/CU (4/SIMD) for latency hiding.
// ---------------------------------------------------------------------------
__global__ __launch_bounds__(512) void qkf_kernel(
    const float* __restrict__ x, const float* __restrict__ Wq,
    const float* __restrict__ Wk, const float* __restrict__ W1,
    float* __restrict__ Qp, float* __restrict__ Kp, float* __restrict__ fcp)
{
    __shared__ __align__(16) u16 SM[6 * 4608];
    u16* Xh  = SM;
    u16* Xl  = SM + 4608;
    u16* Wqh = SM + 2 * 4608;
    u16* Wkh = SM + 3 * 4608;
    u16* W1h = SM + 4 * 4608;
    u16* W1l = SM + 5 * 4608;

    const int tid  = threadIdx.x;
    const int lane = tid & 63;
    const int wv   = tid >> 6;           // 0..7
    const int rt   = (wv & 3) * 16;      // row tile
    const int ch2  = wv >> 2;            // ct half: ct in {2*ch2, 2*ch2+1}
    const long row0 = (long)blockIdx.x * 64;
    const int kb   = blockIdx.y * 512;          // k-half base
    const long sOf = (long)blockIdx.y * 1048576; // output slab offset

    const f32x4 zero = {0.f, 0.f, 0.f, 0.f};
    f32x4 qa[2], ka[2], fa[2];
#pragma unroll
    for (int i = 0; i < 2; ++i) { qa[i] = zero; ka[i] = zero; fa[i] = zero; }

    const int sr = tid >> 4;         // staging row 0..31
    const int sk = (tid & 15) * 4;   // staging k   0..60

    float4 xv[2], qv[2], kv[2], w1v[2];
#define QKF_LOAD(K0)                                                          \
    {                                                                         \
        _Pragma("unroll")                                                     \
        for (int i = 0; i < 2; ++i) {                                         \
            int r = sr + i * 32;                                              \
            xv[i]  = *(const float4*)(x  + (row0 + r) * 1024 + (K0) + sk);    \
            qv[i]  = *(const float4*)(Wq + (long)r * 1024 + (K0) + sk);       \
            kv[i]  = *(const float4*)(Wk + (long)r * 1024 + (K0) + sk);       \
            w1v[i] = *(const float4*)(W1 + (long)r * 1024 + (K0) + sk);       \
        }                                                                     \
    }

    QKF_LOAD(kb)
    for (int ch = 0; ch < 8; ++ch) {
        if (ch) __syncthreads();
#pragma unroll
        for (int i = 0; i < 2; ++i) {
            int r = sr + i * 32;
            ushort4 h, l;
            h.x = f2bf(xv[i].x); l.x = f2bf(xv[i].x - bf2f(h.x));
            h.y = f2bf(xv[i].y); l.y = f2bf(xv[i].y - bf2f(h.y));
            h.z = f2bf(xv[i].z); l.z = f2bf(xv[i].z - bf2f(h.z));
            h.w = f2bf(xv[i].w); l.w = f2bf(xv[i].w - bf2f(h.w));
            *(ushort4*)&Xh[r * 72 + sk] = h;
            *(ushort4*)&Xl[r * 72 + sk] = l;
            ushort4 hq;
            hq.x = f2bf(qv[i].x); hq.y = f2bf(qv[i].y);
            hq.z = f2bf(qv[i].z); hq.w = f2bf(qv[i].w);
            *(ushort4*)&Wqh[r * 72 + sk] = hq;
            ushort4 hk;
            hk.x = f2bf(kv[i].x); hk.y = f2bf(kv[i].y);
            hk.z = f2bf(kv[i].z); hk.w = f2bf(kv[i].w);
            *(ushort4*)&Wkh[r * 72 + sk] = hk;
            ushort4 hw, lw;
            hw.x = f2bf(w1v[i].x); lw.x = f2bf(w1v[i].x - bf2f(hw.x));
            hw.y = f2bf(w1v[i].y); lw.y = f2bf(w1v[i].y - bf2f(hw.y));
            hw.z = f2bf(w1v[i].z); lw.z = f2bf(w1v[i].z - bf2f(hw.z));
            hw.w = f2bf(w1v[i].w); lw.w = f2bf(w1v[i].w - bf2f(hw.w));
            *(ushort4*)&W1h[r * 72 + sk] = hw;
            *(ushort4*)&W1l[r * 72 + sk] = lw;
        }
        __syncthreads();
        if (ch < 7) QKF_LOAD(kb + (ch + 1) * 64)
#pragma unroll
        for (int kk = 0; kk < 64; kk += 32) {
            bf16x8 ah = frag(Xh, rt, lane, kk);
            bf16x8 al = frag(Xl, rt, lane, kk);
#pragma unroll
            for (int c = 0; c < 2; ++c) {
                int ct = ch2 * 2 + c;
                qa[c] = MFMA16(ah, frag(Wqh, ct * 16, lane, kk), qa[c]);
                ka[c] = MFMA16(ah, frag(Wkh, ct * 16, lane, kk), ka[c]);
                bf16x8 bh = frag(W1h, ct * 16, lane, kk);
                fa[c] = MFMA16(ah, bh, fa[c]);
                fa[c] = MFMA16(al, bh, fa[c]);
                fa[c] = MFMA16(ah, frag(W1l, ct * 16, lane, kk), fa[c]);
            }
        }
    }
#undef QKF_LOAD

    // fp32 partial stores (C layout: col=lane&15, row=quad*4+g)
    const int rr = rt + (lane >> 4) * 4;
    const int cc = lane & 15;
#pragma unroll
    for (int c = 0; c < 2; ++c)
#pragma unroll
        for (int g = 0; g < 4; ++g) {
            long o = sOf + (row0 + rr + g) * 64 + (ch2 * 2 + c) * 16 + cc;
            Qp[o]  = qa[c][g];
            Kp[o]  = ka[c][g];
            fcp[o] = fa[c][g];
        }
}

// ---------------------------------------------------------------------------
// Sp[ks][b][j][d] = sum_{n in ks-slice} K[b,n,j] * x[b,n,d]
// K comes as 2 fp32 slabs (summed at staging). grid (16,8,8) = 1024 blocks.
// ---------------------------------------------------------------------------
__global__ __launch_bounds__(256) void s_kernel(
    const float* __restrict__ Kp, const float* __restrict__ x,
    float* __restrict__ Sp)
{
    __shared__ __align__(16) u16 Kt[64 * 72];
    __shared__ __align__(16) u16 Xt[64 * 72];

    const int tid = threadIdx.x, lane = tid & 63, wv = tid >> 6;
    const int dt = blockIdx.x, ks = blockIdx.y, b = blockIdx.z;
    const int n0 = ks * 256, d0 = dt * 64;

    const float* Kq = Kp + ((long)b * 2048 + n0) * 64;
    const float* xp = x  + ((long)b * 2048 + n0) * 1024 + d0;

    const f32x4 zero = {0.f, 0.f, 0.f, 0.f};
    f32x4 acc[4];
#pragma unroll
    for (int i = 0; i < 4; ++i) acc[i] = zero;

    float4 kf[4], xv[4];
#define SK_LOAD(NB)                                                           \
    {                                                                         \
        _Pragma("unroll")                                                     \
        for (int i = 0; i < 4; ++i) {                                         \
            float4 a = *(const float4*)(Kq + (long)((NB) + lane) * 64 + wv * 16 + i * 4); \
            float4 c = *(const float4*)(Kq + 1048576 + (long)((NB) + lane) * 64 + wv * 16 + i * 4); \
            kf[i].x = a.x + c.x; kf[i].y = a.y + c.y;                         \
            kf[i].z = a.z + c.z; kf[i].w = a.w + c.w;                         \
            xv[i] = *(const float4*)(xp + (long)((NB) + lane) * 1024 + wv * 16 + i * 4); \
        }                                                                     \
    }

    SK_LOAD(0)
    for (int ch = 0; ch < 4; ++ch) {
        if (ch) __syncthreads();
#pragma unroll
        for (int i = 0; i < 4; ++i) {
            Kt[(wv * 16 + i * 4 + 0) * 72 + lane] = f2bf(kf[i].x);
            Kt[(wv * 16 + i * 4 + 1) * 72 + lane] = f2bf(kf[i].y);
            Kt[(wv * 16 + i * 4 + 2) * 72 + lane] = f2bf(kf[i].z);
            Kt[(wv * 16 + i * 4 + 3) * 72 + lane] = f2bf(kf[i].w);
            Xt[(wv * 16 + i * 4 + 0) * 72 + lane] = f2bf(xv[i].x);
            Xt[(wv * 16 + i * 4 + 1) * 72 + lane] = f2bf(xv[i].y);
            Xt[(wv * 16 + i * 4 + 2) * 72 + lane] = f2bf(xv[i].z);
            Xt[(wv * 16 + i * 4 + 3) * 72 + lane] = f2bf(xv[i].w);
        }
        __syncthreads();
        if (ch < 3) SK_LOAD((ch + 1) * 64)
#pragma unroll
        for (int kk = 0; kk < 64; kk += 32) {
            bf16x8 a = frag(Kt, wv * 16, lane, kk);
#pragma unroll
            for (int ct = 0; ct < 4; ++ct)
                acc[ct] = MFMA16(a, frag(Xt, ct * 16, lane, kk), acc[ct]);
        }
    }
#undef SK_LOAD

    float* C = Sp + ((long)ks * 8 + b) * 65536 + d0;
    const int rr = wv * 16 + (lane >> 4) * 4;
    const int cc = lane & 15;
#pragma unroll
    for (int ct = 0; ct < 4; ++ct)
#pragma unroll
        for (int g = 0; g < 4; ++g)
            C[(long)(rr + g) * 1024 + ct * 16 + cc] = acc[ct][g];
}

// ---------------------------------------------------------------------------
// 64x64 MFMA NT-GEMM: C[m,n] = sum_s Cin_s[m,n] + sum_k (sum A_s)*(sum B_s)
// AMODE: 0 fp32 row-major, 1 bf16 row-major.
// BMODE: 0 fp32 row-major, 1 bf16 row-major, 2 fp32 transposed [k][n].
// SPLIT: hi/lo 3-product accuracy. CSLAB: #fp32 C-init slabs (0 = none).
// ---------------------------------------------------------------------------
template <int AMODE, int BMODE, bool SPLIT, int ASLAB, int BSLAB, int CSLAB>
__global__ __launch_bounds__(256) void mm_nt(
    const void* __restrict__ Ap, int lda, long bsA, long slabA,
    const void* __restrict__ Bp, int ldb, long bsB, long slabB,
    float* __restrict__ Cp, int ldc, long bsC, long splitC,
    const float* __restrict__ Cin, long slabCin,
    int Kred, int nksplit)
{
    __shared__ __align__(16) u16 SMEM[(SPLIT ? 4 : 2) * 4608];
    u16* Ah = SMEM;
    u16* Bh = SMEM + 4608;
    u16* Al = SPLIT ? SMEM + 2 * 4608 : nullptr;
    u16* Bl = SPLIT ? SMEM + 3 * 4608 : nullptr;

    const int tid = threadIdx.x, lane = tid & 63, wv = tid >> 6;
    const int bm = blockIdx.x, bn = blockIdx.y;
    const int batch = blockIdx.z / nksplit;
    const int ks = blockIdx.z % nksplit;
    const int Kper = Kred / nksplit;
    const long kOff = (long)ks * Kper;

    const int r4 = tid >> 4, k4 = (tid & 15) * 4;   // mode-0 staging coords
    const int r8 = tid >> 3, k8 = (tid & 7) * 8;    // mode-1 staging coords

    const f32x4 zero = {0.f, 0.f, 0.f, 0.f};
    f32x4 acc[4];
#pragma unroll
    for (int i = 0; i < 4; ++i) acc[i] = zero;

    float4 fva[4], fvb[4];
    uint4  uva[2], uvb[2];
    float  tvb[16];

#define MM_LOADA(K0)                                                          \
    if constexpr (AMODE == 0) {                                               \
        const float* A = (const float*)Ap + (long)batch * bsA                 \
                       + (long)bm * 64 * lda + (K0);                          \
        _Pragma("unroll")                                                     \
        for (int i = 0; i < 4; ++i) {                                         \
            const float* p = A + (long)(r4 + i * 16) * lda + k4;              \
            float4 v = *(const float4*)p;                                     \
            _Pragma("unroll")                                                 \
            for (int s = 1; s < ASLAB; ++s) {                                 \
                float4 w = *(const float4*)(p + (long)s * slabA);             \
                v.x += w.x; v.y += w.y; v.z += w.z; v.w += w.w;               \
            }                                                                 \
            fva[i] = v;                                                       \
        }                                                                     \
    } else {                                                                  \
        const u16* A = (const u16*)Ap + (long)batch * bsA                     \
                     + (long)bm * 64 * lda + (K0);                            \
        _Pragma("unroll")                                                     \
        for (int i = 0; i < 2; ++i)                                           \
            uva[i] = *(const uint4*)(A + (long)(r8 + i * 32) * lda + k8);     \
    }
#define MM_LOADB(K0)                                                          \
    if constexpr (BMODE == 0) {                                               \
        const float* Bq = (const float*)Bp + (long)batch * bsB                \
                        + (long)bn * 64 * ldb + (K0);                         \
        _Pragma("unroll")                                                     \
        for (int i = 0; i < 4; ++i) {                                         \
            const float* p = Bq + (long)(r4 + i * 16) * ldb + k4;             \
            float4 v = *(const float4*)p;                                     \
            _Pragma("unroll")                                                 \
            for (int s = 1; s < BSLAB; ++s) {                                 \
                float4 w = *(const float4*)(p + (long)s * slabB);             \
                v.x += w.x; v.y += w.y; v.z += w.z; v.w += w.w;               \
            }                                                                 \
            fvb[i] = v;                                                       \
        }                                                                     \
    } else if constexpr (BMODE == 1) {                                        \
        const u16* Bq = (const u16*)Bp + (long)batch * bsB                    \
                      + (long)bn * 64 * ldb + (K0);                           \
        _Pragma("unroll")                                                     \
        for (int i = 0; i < 2; ++i)                                           \
            uvb[i] = *(const uint4*)(Bq + (long)(r8 + i * 32) * ldb + k8);    \
    } else {                                                                  \
        const float* Bq = (const float*)Bp + (long)batch * bsB                \
                        + (long)(K0) * ldb + (long)bn * 64;                   \
        _Pragma("unroll")                                                     \
        for (int i = 0; i < 16; ++i)                                          \
            tvb[i] = Bq[(long)((tid >> 6) + i * 4) * ldb + (tid & 63)];       \
    }

    MM_LOADA(kOff) MM_LOADB(kOff)
    for (int k0 = 0; k0 < Kper; k0 += 64) {
        if (k0) __syncthreads();
        // ---- store phase A ----
        if constexpr (AMODE == 0) {
#pragma unroll
            for (int i = 0; i < 4; ++i) {
                int r = r4 + i * 16;
                ushort4 h;
                h.x = f2bf(fva[i].x); h.y = f2bf(fva[i].y);
                h.z = f2bf(fva[i].z); h.w = f2bf(fva[i].w);
                *(ushort4*)&Ah[r * 72 + k4] = h;
                if constexpr (SPLIT) {
                    ushort4 l;
                    l.x = f2bf(fva[i].x - bf2f(h.x)); l.y = f2bf(fva[i].y - bf2f(h.y));
                    l.z = f2bf(fva[i].z - bf2f(h.z)); l.w = f2bf(fva[i].w - bf2f(h.w));
                    *(ushort4*)&Al[r * 72 + k4] = l;
                }
            }
        } else {
#pragma unroll
            for (int i = 0; i < 2; ++i)
                *(uint4*)&Ah[(r8 + i * 32) * 72 + k8] = uva[i];
        }
        // ---- store phase B ----
        if constexpr (BMODE == 0) {
#pragma unroll
            for (int i = 0; i < 4; ++i) {
                int r = r4 + i * 16;
                ushort4 h;
                h.x = f2bf(fvb[i].x); h.y = f2bf(fvb[i].y);
                h.z = f2bf(fvb[i].z); h.w = f2bf(fvb[i].w);
                *(ushort4*)&Bh[r * 72 + k4] = h;
                if constexpr (SPLIT) {
                    ushort4 l;
                    l.x = f2bf(fvb[i].x - bf2f(h.x)); l.y = f2bf(fvb[i].y - bf2f(h.y));
                    l.z = f2bf(fvb[i].z - bf2f(h.z)); l.w = f2bf(fvb[i].w - bf2f(h.w));
                    *(ushort4*)&Bl[r * 72 + k4] = l;
                }
            }
        } else if constexpr (BMODE == 1) {
#pragma unroll
            for (int i = 0; i < 2; ++i)
                *(uint4*)&Bh[(r8 + i * 32) * 72 + k8] = uvb[i];
        } else {
#pragma unroll
            for (int i = 0; i < 16; ++i)
                Bh[(tid & 63) * 72 + (tid >> 6) + i * 4] = f2bf(tvb[i]);
        }
        __syncthreads();
        if (k0 + 64 < Kper) { MM_LOADA(kOff + k0 + 64) MM_LOADB(kOff + k0 + 64) }
#pragma unroll
        for (int kk = 0; kk < 64; kk += 32) {
            bf16x8 ah = frag(Ah, wv * 16, lane, kk);
            bf16x8 al;
            if constexpr (SPLIT) al = frag(Al, wv * 16, lane, kk);
#pragma unroll
            for (int ct = 0; ct < 4; ++ct) {
                bf16x8 bh = frag(Bh, ct * 16, lane, kk);
                acc[ct] = MFMA16(ah, bh, acc[ct]);
                if constexpr (SPLIT) {
                    acc[ct] = MFMA16(al, bh, acc[ct]);
                    acc[ct] = MFMA16(ah, frag(Bl, ct * 16, lane, kk), acc[ct]);
                }
            }
        }
    }
#undef MM_LOADA
#undef MM_LOADB

    const long coff = (long)batch * bsC + (long)bm * 64 * ldc + (long)bn * 64;
    float* C = Cp + coff + (long)ks * splitC;
    const int rr = wv * 16 + (lane >> 4) * 4;
    const int cc = lane & 15;
#pragma unroll
    for (int ct = 0; ct < 4; ++ct)
#pragma unroll
        for (int g = 0; g < 4; ++g) {
            long idx = (long)(rr + g) * ldc + ct * 16 + cc;
            float v = acc[ct][g];
            if constexpr (CSLAB > 0) {
                const float* Ci = Cin + coff + idx;
#pragma unroll
                for (int s = 0; s < CSLAB; ++s) v += Ci[(long)s * slabCin];
            }
            C[idx] = v;
        }
}

// ---------------------------------------------------------------------------
extern "C" void kernel_launch(void* const* d_in, const int* in_sizes, int n_in,
                              void* d_out, int out_size, void* d_ws, size_t ws_size,
                              hipStream_t stream)
{
    const float* x  = (const float*)d_in[0];
    const float* Wq = (const float*)d_in[1];
    const float* Wk = (const float*)d_in[2];
    const float* Wv = (const float*)d_in[3];
    const float* W1 = (const float*)d_in[4];
    const float* W2 = (const float*)d_in[5];
    float* out = (float*)d_out;

    // Scratch (bytes): Qp 8M (2 slabs), Kp 8M, fcp 8M, Sp 16M, Gp 2M, PBp 2M, fcb 4M
    const size_t QPB = 8388608, KPB = 8388608, FCPB = 8388608,
                 SPB = 16777216, GPB = 2097152, PBB = 2097152, FCB = 4194304;
    const size_t need = QPB + KPB + FCPB + SPB + GPB + PBB + FCB;  // 50 MB

    float *Qp, *Kp, *fcp, *Sp, *Gp, *PBp, *fcb;
    if (ws_size >= need) {
        char* w = (char*)d_ws;
        Qp  = (float*)w;  w += QPB;
        Kp  = (float*)w;  w += KPB;
        fcp = (float*)w;  w += FCPB;
        Sp  = (float*)w;  w += SPB;
        Gp  = (float*)w;  w += GPB;
        PBp = (float*)w;  w += PBB;
        fcb = (float*)w;
    } else {
        // Scratch in d_out (all dead before the final GEMM overwrites it);
        // fcb (read concurrently with out writes) in ws.
        char* o = (char*)d_out;
        Qp  = (float*)o;  o += QPB;
        Kp  = (float*)o;  o += KPB;
        fcp = (float*)o;  o += FCPB;
        Sp  = (float*)o;  o += SPB;
        Gp  = (float*)o;  o += GPB;
        PBp = (float*)o;
        fcb = (float*)d_ws;
    }

    // 1) Qp/Kp/fcp partials over k-halves (512 blocks x 512 thr, 2 blk/CU)
    qkf_kernel<<<dim3(256, 2), 512, 0, stream>>>(x, Wq, Wk, W1, Qp, Kp, fcp);

    // 2) Sp[ks8][b][j][d] = (Kp0+Kp1)_slice^T * x_slice  (1024 blocks)
    s_kernel<<<dim3(16, 8, 8), 256, 0, stream>>>(Kp, x, Sp);

    // 3) Gpart[ks8][k][d] = W1[k,:] * Wv[:,d]  (batch-independent, 128 blocks)
    mm_nt<0, 2, false, 1, 1, 0><<<dim3(1, 16, 8), 256, 0, stream>>>(
        W1, 1024, 0, 0,   Wv, 1024, 0, 0,
        Gp, 1024, 0, 65536L, nullptr, 0, 1024, 8);

    // 4) PBTpart[ks16][b][k][j] = (sum_8 Gpart)[k,:] * (sum_8 Sp)[b][j,:]^T  (128 blocks)
    mm_nt<0, 0, false, 8, 8, 0><<<dim3(1, 1, 128), 256, 0, stream>>>(
        Gp, 1024, 0, 65536L,   Sp, 1024, 65536L, 524288L,
        PBp, 64, 4096L, 32768L, nullptr, 0, 1024, 16);

    // 5) fcb = fcp0 + fcp1 + (Qp0+Qp1) * (sum_16 PBTpart)^T  (256 blocks)
    mm_nt<0, 0, false, 2, 16, 2><<<dim3(32, 1, 8), 256, 0, stream>>>(
        Qp, 64, 131072L, 1048576L,   PBp, 64, 4096L, 32768L,
        fcb, 64, 131072L, 0, fcp, 1048576L, 64, 1);

    // 6) out = fcb * W2^T (split-accurate both operands, 4096 blocks)
    mm_nt<0, 0, true, 1, 1, 0><<<dim3(256, 16, 1), 256, 0, stream>>>(
        fcb, 64, 0, 0,   W2, 64, 0, 0,
        out, 1024, 0, 0, nullptr, 0, 64, 1);
}

// Round 4
// 208.964 us; speedup vs baseline: 1.0297x; 1.0197x over previous
//
#include <hip/hip_runtime.h>

typedef __attribute__((ext_vector_type(8))) __bf16 bf16x8;
typedef __attribute__((ext_vector_type(4))) float f32x4;
typedef unsigned short u16;

#define MFMA16(a, b, c) __builtin_amdgcn_mfma_f32_16x16x32_bf16(a, b, c, 0, 0, 0)

// HW packed fp32->bf16 (RNE), 2 values per instruction. No builtin on gfx950.
__device__ __forceinline__ unsigned cvt2(float a, float b) {
    unsigned r;
    asm("v_cvt_pk_bf16_f32 %0, %1, %2" : "=v"(r) : "v"(a), "v"(b));
    return r;  // lo16 = bf16(a), hi16 = bf16(b)
}
__device__ __forceinline__ u16 cvt1(float a) { return (u16)cvt2(a, a); }
__device__ __forceinline__ float lo2f(unsigned p) { return __uint_as_float(p << 16); }
__device__ __forceinline__ float hi2f(unsigned p) { return __uint_as_float(p & 0xffff0000u); }

// LDS fragment: row = rtile + (lane&15), k = kofs + (lane>>4)*8; row stride 72 u16 (144B)
__device__ __forceinline__ bf16x8 frag(const u16* base, int rtile, int lane, int kofs) {
    return *(const bf16x8*)(base + (rtile + (lane & 15)) * 72 + kofs + (lane >> 4) * 8);
}

// ---------------------------------------------------------------------------
// Fused partial: for k-half ks (blockIdx.y), 64 rows (blockIdx.x):
//   Qp[ks] = x*Wq^T, Kp[ks] = x*Wk^T (fp32 partials)
//   fcp[ks] = x*W1^T (fp32, 3-product bf16 split)
// 512 threads / 8 waves; x stream 2-deep prefetch (ping-pong reg sets),
// weights 1-deep (L2-resident). cvt_pk staging. 2 blocks/CU.
// ---------------------------------------------------------------------------
__global__ __launch_bounds__(512, 4) void qkf_kernel(
    const float* __restrict__ x, const float* __restrict__ Wq,
    const float* __restrict__ Wk, const float* __restrict__ W1,
    float* __restrict__ Qp, float* __restrict__ Kp, float* __restrict__ fcp)
{
    __shared__ __align__(16) u16 SM[6 * 4608];
    u16* Xh  = SM;
    u16* Xl  = SM + 4608;
    u16* Wqh = SM + 2 * 4608;
    u16* Wkh = SM + 3 * 4608;
    u16* W1h = SM + 4 * 4608;
    u16* W1l = SM + 5 * 4608;

    const int tid  = threadIdx.x;
    const int lane = tid & 63;
    const int wv   = tid >> 6;           // 0..7
    const int rt   = (wv & 3) * 16;      // row tile
    const int ch2  = wv >> 2;            // ct half: ct in {2*ch2, 2*ch2+1}
    const long row0 = (long)blockIdx.x * 64;
    const int kb   = blockIdx.y * 512;          // k-half base
    const long sOf = (long)blockIdx.y * 1048576; // output slab offset

    const f32x4 zero = {0.f, 0.f, 0.f, 0.f};
    f32x4 qa[2], ka[2], fa[2];
#pragma unroll
    for (int i = 0; i < 2; ++i) { qa[i] = zero; ka[i] = zero; fa[i] = zero; }

    const int sr = tid >> 4;         // staging row 0..31
    const int sk = (tid & 15) * 4;   // staging k   0..60

    float4 xv0[2], xv1[2], qv[2], kv[2], w1v[2];

#define LOAD_X(S, K0)                                                         \
    { _Pragma("unroll")                                                       \
      for (int i = 0; i < 2; ++i)                                             \
          xv##S[i] = *(const float4*)(x + (row0 + sr + i * 32) * 1024 + (K0) + sk); }
#define LOAD_W(K0)                                                            \
    { _Pragma("unroll")                                                       \
      for (int i = 0; i < 2; ++i) {                                           \
          int r = sr + i * 32;                                                \
          qv[i]  = *(const float4*)(Wq + (long)r * 1024 + (K0) + sk);         \
          kv[i]  = *(const float4*)(Wk + (long)r * 1024 + (K0) + sk);         \
          w1v[i] = *(const float4*)(W1 + (long)r * 1024 + (K0) + sk);         \
      } }
#define CONV(S)                                                               \
    { _Pragma("unroll")                                                       \
      for (int i = 0; i < 2; ++i) {                                           \
          int r = sr + i * 32;                                                \
          unsigned xh01 = cvt2(xv##S[i].x, xv##S[i].y);                       \
          unsigned xh23 = cvt2(xv##S[i].z, xv##S[i].w);                       \
          unsigned xl01 = cvt2(xv##S[i].x - lo2f(xh01), xv##S[i].y - hi2f(xh01)); \
          unsigned xl23 = cvt2(xv##S[i].z - lo2f(xh23), xv##S[i].w - hi2f(xh23)); \
          uint2 t;                                                            \
          t.x = xh01; t.y = xh23; *(uint2*)&Xh[r * 72 + sk] = t;              \
          t.x = xl01; t.y = xl23; *(uint2*)&Xl[r * 72 + sk] = t;              \
          t.x = cvt2(qv[i].x, qv[i].y); t.y = cvt2(qv[i].z, qv[i].w);         \
          *(uint2*)&Wqh[r * 72 + sk] = t;                                     \
          t.x = cvt2(kv[i].x, kv[i].y); t.y = cvt2(kv[i].z, kv[i].w);         \
          *(uint2*)&Wkh[r * 72 + sk] = t;                                     \
          unsigned wh01 = cvt2(w1v[i].x, w1v[i].y);                           \
          unsigned wh23 = cvt2(w1v[i].z, w1v[i].w);                           \
          unsigned wl01 = cvt2(w1v[i].x - lo2f(wh01), w1v[i].y - hi2f(wh01)); \
          unsigned wl23 = cvt2(w1v[i].z - lo2f(wh23), w1v[i].w - hi2f(wh23)); \
          t.x = wh01; t.y = wh23; *(uint2*)&W1h[r * 72 + sk] = t;             \
          t.x = wl01; t.y = wl23; *(uint2*)&W1l[r * 72 + sk] = t;             \
      } }
#define MFMA_PHASE                                                            \
    { _Pragma("unroll")                                                       \
      for (int kk = 0; kk < 64; kk += 32) {                                   \
          bf16x8 ah = frag(Xh, rt, lane, kk);                                 \
          bf16x8 al = frag(Xl, rt, lane, kk);                                 \
          _Pragma("unroll")                                                   \
          for (int c = 0; c < 2; ++c) {                                       \
              int ct = ch2 * 2 + c;                                           \
              qa[c] = MFMA16(ah, frag(Wqh, ct * 16, lane, kk), qa[c]);        \
              ka[c] = MFMA16(ah, frag(Wkh, ct * 16, lane, kk), ka[c]);        \
              bf16x8 bh = frag(W1h, ct * 16, lane, kk);                       \
              fa[c] = MFMA16(ah, bh, fa[c]);                                  \
              fa[c] = MFMA16(al, bh, fa[c]);                                  \
              fa[c] = MFMA16(ah, frag(W1l, ct * 16, lane, kk), fa[c]);        \
          }                                                                   \
      } }

    // Prologue: x chunks 0,1 + weights chunk 0
    LOAD_X(0, kb) LOAD_X(1, kb + 64) LOAD_W(kb)

    for (int cp = 0; cp < 4; ++cp) {     // chunk pair (2cp, 2cp+1)
        const int kc = kb + cp * 128;
        // ---- chunk 2cp (x set 0) ----
        if (cp) __syncthreads();
        CONV(0)
        __syncthreads();
        if (cp < 3) LOAD_X(0, kc + 128)   // x chunk 2cp+2
        LOAD_W(kc + 64)                   // weights chunk 2cp+1
        MFMA_PHASE
        // ---- chunk 2cp+1 (x set 1) ----
        __syncthreads();
        CONV(1)
        __syncthreads();
        if (cp < 3) { LOAD_X(1, kc + 192) LOAD_W(kc + 128) }  // x 2cp+3, W 2cp+2
        MFMA_PHASE
    }
#undef LOAD_X
#undef LOAD_W
#undef CONV
#undef MFMA_PHASE

    // fp32 partial stores (C layout: col=lane&15, row=quad*4+g)
    const int rr = rt + (lane >> 4) * 4;
    const int cc = lane & 15;
#pragma unroll
    for (int c = 0; c < 2; ++c)
#pragma unroll
        for (int g = 0; g < 4; ++g) {
            long o = sOf + (row0 + rr + g) * 64 + (ch2 * 2 + c) * 16 + cc;
            Qp[o]  = qa[c][g];
            Kp[o]  = ka[c][g];
            fcp[o] = fa[c][g];
        }
}

// ---------------------------------------------------------------------------
// Sp[ks][b][j][d] = sum_{n in ks-slice} K[b,n,j] * x[b,n,d]
// K comes as 2 fp32 slabs (summed at staging). grid (16,8,8) = 1024 blocks.
// ---------------------------------------------------------------------------
__global__ __launch_bounds__(256) void s_kernel(
    const float* __restrict__ Kp, const float* __restrict__ x,
    float* __restrict__ Sp)
{
    __shared__ __align__(16) u16 Kt[64 * 72];
    __shared__ __align__(16) u16 Xt[64 * 72];

    const int tid = threadIdx.x, lane = tid & 63, wv = tid >> 6;
    const int dt = blockIdx.x, ks = blockIdx.y, b = blockIdx.z;
    const int n0 = ks * 256, d0 = dt * 64;

    const float* Kq = Kp + ((long)b * 2048 + n0) * 64;
    const float* xp = x  + ((long)b * 2048 + n0) * 1024 + d0;

    const f32x4 zero = {0.f, 0.f, 0.f, 0.f};
    f32x4 acc[4];
#pragma unroll
    for (int i = 0; i < 4; ++i) acc[i] = zero;

    float4 kf[4], xv[4];
#define SK_LOAD(NB)                                                           \
    {                                                                         \
        _Pragma("unroll")                                                     \
        for (int i = 0; i < 4; ++i) {                                         \
            float4 a = *(const float4*)(Kq + (long)((NB) + lane) * 64 + wv * 16 + i * 4); \
            float4 c = *(const float4*)(Kq + 1048576 + (long)((NB) + lane) * 64 + wv * 16 + i * 4); \
            kf[i].x = a.x + c.x; kf[i].y = a.y + c.y;                         \
            kf[i].z = a.z + c.z; kf[i].w = a.w + c.w;                         \
            xv[i] = *(const float4*)(xp + (long)((NB) + lane) * 1024 + wv * 16 + i * 4); \
        }                                                                     \
    }

    SK_LOAD(0)
    for (int ch = 0; ch < 4; ++ch) {
        if (ch) __syncthreads();
#pragma unroll
        for (int i = 0; i < 4; ++i) {
            Kt[(wv * 16 + i * 4 + 0) * 72 + lane] = cvt1(kf[i].x);
            Kt[(wv * 16 + i * 4 + 1) * 72 + lane] = cvt1(kf[i].y);
            Kt[(wv * 16 + i * 4 + 2) * 72 + lane] = cvt1(kf[i].z);
            Kt[(wv * 16 + i * 4 + 3) * 72 + lane] = cvt1(kf[i].w);
            Xt[(wv * 16 + i * 4 + 0) * 72 + lane] = cvt1(xv[i].x);
            Xt[(wv * 16 + i * 4 + 1) * 72 + lane] = cvt1(xv[i].y);
            Xt[(wv * 16 + i * 4 + 2) * 72 + lane] = cvt1(xv[i].z);
            Xt[(wv * 16 + i * 4 + 3) * 72 + lane] = cvt1(xv[i].w);
        }
        __syncthreads();
        if (ch < 3) SK_LOAD((ch + 1) * 64)
#pragma unroll
        for (int kk = 0; kk < 64; kk += 32) {
            bf16x8 a = frag(Kt, wv * 16, lane, kk);
#pragma unroll
            for (int ct = 0; ct < 4; ++ct)
                acc[ct] = MFMA16(a, frag(Xt, ct * 16, lane, kk), acc[ct]);
        }
    }
#undef SK_LOAD

    float* C = Sp + ((long)ks * 8 + b) * 65536 + d0;
    const int rr = wv * 16 + (lane >> 4) * 4;
    const int cc = lane & 15;
#pragma unroll
    for (int ct = 0; ct < 4; ++ct)
#pragma unroll
        for (int g = 0; g < 4; ++g)
            C[(long)(rr + g) * 1024 + ct * 16 + cc] = acc[ct][g];
}

// ---------------------------------------------------------------------------
// 64x64 MFMA NT-GEMM: C[m,n] = sum_s Cin_s[m,n] + sum_k (sum A_s)*(sum B_s)
// AMODE: 0 fp32 row-major, 1 bf16 row-major.
// BMODE: 0 fp32 row-major, 1 bf16 row-major, 2 fp32 transposed [k][n].
// SPLIT: hi/lo 3-product accuracy. CSLAB: #fp32 C-init slabs (0 = none).
// ---------------------------------------------------------------------------
template <int AMODE, int BMODE, bool SPLIT, int ASLAB, int BSLAB, int CSLAB>
__global__ __launch_bounds__(256) void mm_nt(
    const void* __restrict__ Ap, int lda, long bsA, long slabA,
    const void* __restrict__ Bp, int ldb, long bsB, long slabB,
    float* __restrict__ Cp, int ldc, long bsC, long splitC,
    const float* __restrict__ Cin, long slabCin,
    int Kred, int nksplit)
{
    __shared__ __align__(16) u16 SMEM[(SPLIT ? 4 : 2) * 4608];
    u16* Ah = SMEM;
    u16* Bh = SMEM + 4608;
    u16* Al = SPLIT ? SMEM + 2 * 4608 : nullptr;
    u16* Bl = SPLIT ? SMEM + 3 * 4608 : nullptr;

    const int tid = threadIdx.x, lane = tid & 63, wv = tid >> 6;
    const int bm = blockIdx.x, bn = blockIdx.y;
    const int batch = blockIdx.z / nksplit;
    const int ks = blockIdx.z % nksplit;
    const int Kper = Kred / nksplit;
    const long kOff = (long)ks * Kper;

    const int r4 = tid >> 4, k4 = (tid & 15) * 4;   // mode-0 staging coords
    const int r8 = tid >> 3, k8 = (tid & 7) * 8;    // mode-1 staging coords

    const f32x4 zero = {0.f, 0.f, 0.f, 0.f};
    f32x4 acc[4];
#pragma unroll
    for (int i = 0; i < 4; ++i) acc[i] = zero;

    float4 fva[4], fvb[4];
    uint4  uva[2], uvb[2];
    float  tvb[16];

#define MM_LOADA(K0)                                                          \
    if constexpr (AMODE == 0) {                                               \
        const float* A = (const float*)Ap + (long)batch * bsA                 \
                       + (long)bm * 64 * lda + (K0);                          \
        _Pragma("unroll")                                                     \
        for (int i = 0; i < 4; ++i) {                                         \
            const float* p = A + (long)(r4 + i * 16) * lda + k4;              \
            float4 v = *(const float4*)p;                                     \
            _Pragma("unroll")                                                 \
            for (int s = 1; s < ASLAB; ++s) {                                 \
                float4 w = *(const float4*)(p + (long)s * slabA);             \
                v.x += w.x; v.y += w.y; v.z += w.z; v.w += w.w;               \
            }                                                                 \
            fva[i] = v;                                                       \
        }                                                                     \
    } else {                                                                  \
        const u16* A = (const u16*)Ap + (long)batch * bsA                     \
                     + (long)bm * 64 * lda + (K0);                            \
        _Pragma("unroll")                                                     \
        for (int i = 0; i < 2; ++i)                                           \
            uva[i] = *(const uint4*)(A + (long)(r8 + i * 32) * lda + k8);     \
    }
#define MM_LOADB(K0)                                                          \
    if constexpr (BMODE == 0) {                                               \
        const float* Bq = (const float*)Bp + (long)batch * bsB                \
                        + (long)bn * 64 * ldb + (K0);                         \
        _Pragma("unroll")                                                     \
        for (int i = 0; i < 4; ++i) {                                         \
            const float* p = Bq + (long)(r4 + i * 16) * ldb + k4;             \
            float4 v = *(const float4*)p;                                     \
            _Pragma("unroll")                                                 \
            for (int s = 1; s < BSLAB; ++s) {                                 \
                float4 w = *(const float4*)(p + (long)s * slabB);             \
                v.x += w.x; v.y += w.y; v.z += w.z; v.w += w.w;               \
            }                                                                 \
            fvb[i] = v;                                                       \
        }                                                                     \
    } else if constexpr (BMODE == 1) {                                        \
        const u16* Bq = (const u16*)Bp + (long)batch * bsB                    \
                      + (long)bn * 64 * ldb + (K0);                           \
        _Pragma("unroll")                                                     \
        for (int i = 0; i < 2; ++i)                                           \
            uvb[i] = *(const uint4*)(Bq + (long)(r8 + i * 32) * ldb + k8);    \
    } else {                                                                  \
        const float* Bq = (const float*)Bp + (long)batch * bsB                \
                        + (long)(K0) * ldb + (long)bn * 64;                   \
        _Pragma("unroll")                                                     \
        for (int i = 0; i < 16; ++i)                                          \
            tvb[i] = Bq[(long)((tid >> 6) + i * 4) * ldb + (tid & 63)];       \
    }

    MM_LOADA(kOff) MM_LOADB(kOff)
    for (int k0 = 0; k0 < Kper; k0 += 64) {
        if (k0) __syncthreads();
        // ---- store phase A ----
        if constexpr (AMODE == 0) {
#pragma unroll
            for (int i = 0; i < 4; ++i) {
                int r = r4 + i * 16;
                unsigned h01 = cvt2(fva[i].x, fva[i].y);
                unsigned h23 = cvt2(fva[i].z, fva[i].w);
                uint2 t; t.x = h01; t.y = h23;
                *(uint2*)&Ah[r * 72 + k4] = t;
                if constexpr (SPLIT) {
                    t.x = cvt2(fva[i].x - lo2f(h01), fva[i].y - hi2f(h01));
                    t.y = cvt2(fva[i].z - lo2f(h23), fva[i].w - hi2f(h23));
                    *(uint2*)&Al[r * 72 + k4] = t;
                }
            }
        } else {
#pragma unroll
            for (int i = 0; i < 2; ++i)
                *(uint4*)&Ah[(r8 + i * 32) * 72 + k8] = uva[i];
        }
        // ---- store phase B ----
        if constexpr (BMODE == 0) {
#pragma unroll
            for (int i = 0; i < 4; ++i) {
                int r = r4 + i * 16;
                unsigned h01 = cvt2(fvb[i].x, fvb[i].y);
                unsigned h23 = cvt2(fvb[i].z, fvb[i].w);
                uint2 t; t.x = h01; t.y = h23;
                *(uint2*)&Bh[r * 72 + k4] = t;
                if constexpr (SPLIT) {
                    t.x = cvt2(fvb[i].x - lo2f(h01), fvb[i].y - hi2f(h01));
                    t.y = cvt2(fvb[i].z - lo2f(h23), fvb[i].w - hi2f(h23));
                    *(uint2*)&Bl[r * 72 + k4] = t;
                }
            }
        } else if constexpr (BMODE == 1) {
#pragma unroll
            for (int i = 0; i < 2; ++i)
                *(uint4*)&Bh[(r8 + i * 32) * 72 + k8] = uvb[i];
        } else {
#pragma unroll
            for (int i = 0; i < 16; ++i)
                Bh[(tid & 63) * 72 + (tid >> 6) + i * 4] = cvt1(tvb[i]);
        }
        __syncthreads();
        if (k0 + 64 < Kper) { MM_LOADA(kOff + k0 + 64) MM_LOADB(kOff + k0 + 64) }
#pragma unroll
        for (int kk = 0; kk < 64; kk += 32) {
            bf16x8 ah = frag(Ah, wv * 16, lane, kk);
            bf16x8 al;
            if constexpr (SPLIT) al = frag(Al, wv * 16, lane, kk);
#pragma unroll
            for (int ct = 0; ct < 4; ++ct) {
                bf16x8 bh = frag(Bh, ct * 16, lane, kk);
                acc[ct] = MFMA16(ah, bh, acc[ct]);
                if constexpr (SPLIT) {
                    acc[ct] = MFMA16(al, bh, acc[ct]);
                    acc[ct] = MFMA16(ah, frag(Bl, ct * 16, lane, kk), acc[ct]);
                }
            }
        }
    }
#undef MM_LOADA
#undef MM_LOADB

    const long coff = (long)batch * bsC + (long)bm * 64 * ldc + (long)bn * 64;
    float* C = Cp + coff + (long)ks * splitC;
    const int rr = wv * 16 + (lane >> 4) * 4;
    const int cc = lane & 15;
#pragma unroll
    for (int ct = 0; ct < 4; ++ct)
#pragma unroll
        for (int g = 0; g < 4; ++g) {
            long idx = (long)(rr + g) * ldc + ct * 16 + cc;
            float v = acc[ct][g];
            if constexpr (CSLAB > 0) {
                const float* Ci = Cin + coff + idx;
#pragma unroll
                for (int s = 0; s < CSLAB; ++s) v += Ci[(long)s * slabCin];
            }
            C[idx] = v;
        }
}

// ---------------------------------------------------------------------------
extern "C" void kernel_launch(void* const* d_in, const int* in_sizes, int n_in,
                              void* d_out, int out_size, void* d_ws, size_t ws_size,
                              hipStream_t stream)
{
    const float* x  = (const float*)d_in[0];
    const float* Wq = (const float*)d_in[1];
    const float* Wk = (const float*)d_in[2];
    const float* Wv = (const float*)d_in[3];
    const float* W1 = (const float*)d_in[4];
    const float* W2 = (const float*)d_in[5];
    float* out = (float*)d_out;

    // Scratch (bytes): Qp 8M (2 slabs), Kp 8M, fcp 8M, Sp 16M, Gp 2M, PBp 2M, fcb 4M
    const size_t QPB = 8388608, KPB = 8388608, FCPB = 8388608,
                 SPB = 16777216, GPB = 2097152, PBB = 2097152, FCB = 4194304;
    const size_t need = QPB + KPB + FCPB + SPB + GPB + PBB + FCB;  // 50 MB

    float *Qp, *Kp, *fcp, *Sp, *Gp, *PBp, *fcb;
    if (ws_size >= need) {
        char* w = (char*)d_ws;
        Qp  = (float*)w;  w += QPB;
        Kp  = (float*)w;  w += KPB;
        fcp = (float*)w;  w += FCPB;
        Sp  = (float*)w;  w += SPB;
        Gp  = (float*)w;  w += GPB;
        PBp = (float*)w;  w += PBB;
        fcb = (float*)w;
    } else {
        // Scratch in d_out (all dead before the final GEMM overwrites it);
        // fcb (read concurrently with out writes) in ws.
        char* o = (char*)d_out;
        Qp  = (float*)o;  o += QPB;
        Kp  = (float*)o;  o += KPB;
        fcp = (float*)o;  o += FCPB;
        Sp  = (float*)o;  o += SPB;
        Gp  = (float*)o;  o += GPB;
        PBp = (float*)o;
        fcb = (float*)d_ws;
    }

    // 1) Qp/Kp/fcp partials over k-halves (512 blocks x 512 thr, 2 blk/CU)
    qkf_kernel<<<dim3(256, 2), 512, 0, stream>>>(x, Wq, Wk, W1, Qp, Kp, fcp);

    // 2) Sp[ks8][b][j][d] = (Kp0+Kp1)_slice^T * x_slice  (1024 blocks)
    s_kernel<<<dim3(16, 8, 8), 256, 0, stream>>>(Kp, x, Sp);

    // 3) Gpart[ks8][k][d] = W1[k,:] * Wv[:,d]  (batch-independent, 128 blocks)
    mm_nt<0, 2, false, 1, 1, 0><<<dim3(1, 16, 8), 256, 0, stream>>>(
        W1, 1024, 0, 0,   Wv, 1024, 0, 0,
        Gp, 1024, 0, 65536L, nullptr, 0, 1024, 8);

    // 4) PBTpart[ks16][b][k][j] = (sum_8 Gpart)[k,:] * (sum_8 Sp)[b][j,:]^T  (128 blocks)
    mm_nt<0, 0, false, 8, 8, 0><<<dim3(1, 1, 128), 256, 0, stream>>>(
        Gp, 1024, 0, 65536L,   Sp, 1024, 65536L, 524288L,
        PBp, 64, 4096L, 32768L, nullptr, 0, 1024, 16);

    // 5) fcb = fcp0 + fcp1 + (Qp0+Qp1) * (sum_16 PBTpart)^T  (256 blocks)
    mm_nt<0, 0, false, 2, 16, 2><<<dim3(32, 1, 8), 256, 0, stream>>>(
        Qp, 64, 131072L, 1048576L,   PBp, 64, 4096L, 32768L,
        fcb, 64, 131072L, 0, fcp, 1048576L, 64, 1);

    // 6) out = fcb * W2^T (split-accurate both operands, 4096 blocks)
    mm_nt<0, 0, true, 1, 1, 0><<<dim3(256, 16, 1), 256, 0, stream>>>(
        fcb, 64, 0, 0,   W2, 64, 0, 0,
        out, 1024, 0, 0, nullptr, 0, 64, 1);
}